// Round 14
// baseline (536.615 us; speedup 1.0000x reference)
//
#include <hip/hip_runtime.h>
#include <hip/hip_bf16.h>
#include <hip/hip_cooperative_groups.h>
#include <math.h>

namespace cg = cooperative_groups;

#define NEG 0.2f
#define BSH 6                 // bucket = dst >> 6  (64 dsts per bucket)
#define EPB 2048              // edges per hist/scatter block (416 blocks)

typedef __attribute__((ext_vector_type(4))) float f4;
typedef __attribute__((ext_vector_type(8))) short s8;

__device__ __forceinline__ short f2bf(float f) {
    unsigned u = __float_as_uint(f);
    u += 0x7fff + ((u >> 16) & 1);          // round-to-nearest-even
    return (short)(u >> 16);
}
__device__ __forceinline__ unsigned pk2(float a, float b) {
    union { __hip_bfloat162 h; unsigned u; } c;
    c.h = __float22bfloat162_rn(make_float2(a, b));   // v_cvt_pk_bf16_f32
    return c.u;
}
__device__ __forceinline__ float bf2f(unsigned short s) {
    return __uint_as_float(((unsigned)s) << 16);
}

// helper: one WAVE (lanes t<64) computes the exclusive scan of bsum[0..NCH)
// into bexc_l[] in LDS (NCH <= 384: 64-wide scan rounds with carry).
__device__ __forceinline__ void bexc_scan_wave(const int* __restrict__ bsum,
                                               int* bexc_l, int NCH, int t)
{
    if (t < 64) {
        int carry = 0;
        for (int base = 0; base < NCH; base += 64) {
            int i = base + t;
            int v = (i < NCH) ? bsum[i] : 0;
            int val = v;
#pragma unroll
            for (int o = 1; o < 64; o <<= 1) {
                int u = __shfl_up(val, o);
                if (t >= o) val += u;
            }
            if (i < NCH) bexc_l[i] = carry + val - v;
            carry += __shfl(val, 63);
        }
    }
}

// GEMM body shared by mega and fallback (8 waves, 128 nodes x 256 ch).
__device__ __forceinline__ void gemm_body(
    char* smem, int t, int n0,
    const float* __restrict__ x, const short* __restrict__ Wt,
    const float* __restrict__ att_src, const float* __restrict__ att_dst,
    short* __restrict__ hb, float* __restrict__ a_src_n,
    float* __restrict__ a_dst_n, int M)
{
    short (*xs)[128][32] = (short (*)[128][32])smem;   // [2][128][32] dbuf
    const int lane = t & 63, wv = t >> 6;
    const int wr = wv >> 2;
    const int hd = wv & 3;
    const int quad = lane >> 4, l15 = lane & 15;

    const int row = t >> 2, kq = t & 3;
    const bool okr = (n0 + row) < M;
    const float* xp = x + (size_t)(n0 + row) * 256 + kq * 8;
    const short* wbase = Wt + (size_t)(hd * 64 + l15) * 256 + quad * 8;

    f4 acc[4][4];
#pragma unroll
    for (int i = 0; i < 4; ++i)
#pragma unroll
        for (int j = 0; j < 4; ++j) acc[i][j] = (f4)(0.f);

    float4 v0 = {}, v1 = {};
    if (okr) { const float4* p = (const float4*)xp; v0 = p[0]; v1 = p[1]; }

    s8 af[4];
#pragma unroll
    for (int i = 0; i < 4; ++i)
        af[i] = *(const s8*)(wbase + (size_t)(i * 16) * 256);

    int buf = 0;
#pragma unroll
    for (int ks = 0; ks < 8; ++ks) {
        uint4 u = { pk2(v0.x, v0.y), pk2(v0.z, v0.w), pk2(v1.x, v1.y), pk2(v1.z, v1.w) };
        *(uint4*)&xs[buf][row][kq * 8] = u;
        __syncthreads();

        if (ks < 7 && okr) {
            const float4* p = (const float4*)(xp + (ks + 1) * 32);
            v0 = p[0]; v1 = p[1];
        }
        s8 afn[4];
        if (ks < 7) {
#pragma unroll
            for (int i = 0; i < 4; ++i)
                afn[i] = *(const s8*)(wbase + (size_t)(i * 16) * 256 + (ks + 1) * 32);
        }
        s8 bf[4];
#pragma unroll
        for (int j = 0; j < 4; ++j)
            bf[j] = *(const s8*)&xs[buf][wr * 64 + j * 16 + l15][quad * 8];
#pragma unroll
        for (int i = 0; i < 4; ++i)
#pragma unroll
            for (int j = 0; j < 4; ++j)
                acc[i][j] = __builtin_amdgcn_mfma_f32_16x16x32_bf16(af[i], bf[j], acc[i][j], 0, 0, 0);
        if (ks < 7) {
#pragma unroll
            for (int i = 0; i < 4; ++i) af[i] = afn[i];
        }
        buf ^= 1;
    }

    float asv[4][4], adv[4][4];
#pragma unroll
    for (int i = 0; i < 4; ++i)
#pragma unroll
        for (int rr = 0; rr < 4; ++rr) {
            asv[i][rr] = att_src[hd * 64 + i * 16 + quad * 4 + rr];
            adv[i][rr] = att_dst[hd * 64 + i * 16 + quad * 4 + rr];
        }
#pragma unroll
    for (int j = 0; j < 4; ++j) {
        const int node = n0 + wr * 64 + j * 16 + l15;
        const bool ok = node < M;
        float ps = 0.f, pd = 0.f;
#pragma unroll
        for (int i = 0; i < 4; ++i)
#pragma unroll
            for (int rr = 0; rr < 4; ++rr) {
                float v = acc[i][j][rr];
                ps = fmaf(v, asv[i][rr], ps);
                pd = fmaf(v, adv[i][rr], pd);
            }
        ps += __shfl_xor(ps, 16); ps += __shfl_xor(ps, 32);
        pd += __shfl_xor(pd, 16); pd += __shfl_xor(pd, 32);
        if (ok && quad == 0) {
            a_src_n[node * 4 + hd] = ps;
            a_dst_n[node * 4 + hd] = pd;
        }
        if (ok) {
#pragma unroll
            for (int i = 0; i < 4; ++i) {
                uint2 pk = make_uint2(pk2(acc[i][j][0], acc[i][j][1]),
                                      pk2(acc[i][j][2], acc[i][j][3]));
                *(uint2*)&hb[(size_t)node * 256 + hd * 64 + i * 16 + quad * 4] = pk;
            }
        }
    }
}

// scatter body shared by mega and fallback.
__device__ __forceinline__ void scatter_body(
    char* smem, int t, int cblk,
    const int* __restrict__ ei, const int* __restrict__ scannedT,
    const int* __restrict__ bsum, unsigned* __restrict__ bucketed,
    int E, int N, int NBUCK, int NB, int NCH)
{
    int* bexc_l = (int*)smem;                  // 384 ints
    int* lcur   = (int*)smem + 384;            // NBUCK ints
    bexc_scan_wave(bsum, bexc_l, NCH, t);
    __syncthreads();
    const int* srow = scannedT + (size_t)cblk * NBUCK;
    for (int b = t; b < NBUCK; b += 512)       // coalesced preload
        lcur[b] = srow[b] + bexc_l[(b * NB + cblk) >> 10];
    __syncthreads();
    const int e0 = cblk * EPB, Etot = E + N;
    if (e0 + EPB <= E) {                       // fast path: one int4/thread
        int e = e0 + t * 4;
        int4 s4 = *(const int4*)(ei + e);
        int4 d4 = *(const int4*)(ei + E + e);
        int p0 = atomicAdd(&lcur[d4.x >> BSH], 1);
        bucketed[p0] = (unsigned)s4.x | ((unsigned)(d4.x & 63) << 20);
        int p1 = atomicAdd(&lcur[d4.y >> BSH], 1);
        bucketed[p1] = (unsigned)s4.y | ((unsigned)(d4.y & 63) << 20);
        int p2 = atomicAdd(&lcur[d4.z >> BSH], 1);
        bucketed[p2] = (unsigned)s4.z | ((unsigned)(d4.z & 63) << 20);
        int p3 = atomicAdd(&lcur[d4.w >> BSH], 1);
        bucketed[p3] = (unsigned)s4.w | ((unsigned)(d4.w & 63) << 20);
    } else {
        for (int i = 0; i < EPB / 512; ++i) {
            int e = e0 + i * 512 + t;
            if (e < Etot) {
                int src, dte;
                if (e < E) { src = ei[e]; dte = ei[E + e]; }
                else       { src = e - E; dte = src; }
                int pos = atomicAdd(&lcur[dte >> BSH], 1);
                bucketed[pos] = (unsigned)src | ((unsigned)(dte & 63) << 20);
            }
        }
    }
}

// csr body shared by mega and fallback (512 threads, 8 cursor rows).
__device__ __forceinline__ void csr_body(
    char* smem, int t, int b,
    const unsigned* __restrict__ bucketed, const int* __restrict__ scannedT,
    const int* __restrict__ bsum, int* __restrict__ off, int* __restrict__ csr,
    int N, int NB, int NBUCK, int Etot, int NCH)
{
    unsigned* est = (unsigned*)smem;               // 2048 -> 8192 B
    int* ldeg8  = (int*)(smem + 8192);             // 512  -> 2048 B
    int* lcur8  = (int*)(smem + 10240);            // 512  -> 2048 B
    int* loff   = (int*)(smem + 12288);            // 64   -> 256 B
    int* bexc_l = (int*)(smem + 12544);            // 384  -> 1536 B (14080 total)
    const int wv = t >> 6;

    bexc_scan_wave(bsum, bexc_l, NCH, t);
    ldeg8[(t >> 6) * 64 + (t & 63)] = 0;
    __syncthreads();

    const int gbase = scannedT[b] + bexc_l[(b * NB) >> 10];
    int gend;
    if (b + 1 == NBUCK) gend = Etot;
    else gend = scannedT[b + 1] + bexc_l[((b + 1) * NB) >> 10];
    int cnt = gend - gbase;
    if (cnt > 2048) cnt = 2048;

    for (int i = t; i < cnt; i += 512) {
        unsigned en = bucketed[gbase + i];
        est[i] = en;
        atomicAdd(&ldeg8[wv * 64 + (en >> 20)], 1);
    }
    __syncthreads();
    if (t < 64) {
        int d0 = ldeg8[0 * 64 + t], d1 = ldeg8[1 * 64 + t], d2 = ldeg8[2 * 64 + t], d3 = ldeg8[3 * 64 + t];
        int d4 = ldeg8[4 * 64 + t], d5 = ldeg8[5 * 64 + t], d6 = ldeg8[6 * 64 + t], d7 = ldeg8[7 * 64 + t];
        int tot = d0 + d1 + d2 + d3 + d4 + d5 + d6 + d7;
        int val = tot;
#pragma unroll
        for (int o = 1; o < 64; o <<= 1) {
            int u = __shfl_up(val, o);
            if (t >= o) val += u;
        }
        int excl = val - tot;
        loff[t] = excl;
        int c = excl;
        lcur8[0 * 64 + t] = c; c += d0;
        lcur8[1 * 64 + t] = c; c += d1;
        lcur8[2 * 64 + t] = c; c += d2;
        lcur8[3 * 64 + t] = c; c += d3;
        lcur8[4 * 64 + t] = c; c += d4;
        lcur8[5 * 64 + t] = c; c += d5;
        lcur8[6 * 64 + t] = c; c += d6;
        lcur8[7 * 64 + t] = c;
    }
    __syncthreads();
    for (int i = t; i < cnt; i += 512) {
        unsigned en = est[i];
        int pos = atomicAdd(&lcur8[wv * 64 + (en >> 20)], 1);
        csr[gbase + pos] = (int)(en & 0xFFFFF);
    }
    if (t < 64) {
        int n = (b << BSH) + t;
        if (n < N) off[n] = gbase + loff[t];
    }
}

// ---------------------------------------------------------------------------
// MEGA: entire build chain in ONE cooperative kernel. 4 phases:
//  A: Wt transpose (128 units) + 2D histogram (NB units)
//  B: scan (NCH units) || GEMM (GB units)  — gemm rides scan's idle blocks
//  C: scatter (NB units)
//  D: csr_build (NBUCK units)
// Saves 3 kernel boundaries; grid-stride loops tolerate any grid size.
// ---------------------------------------------------------------------------
__global__ __launch_bounds__(512) void mega(
    const float* __restrict__ x, const float* __restrict__ W,
    short* __restrict__ Wt,
    const float* __restrict__ att_src, const float* __restrict__ att_dst,
    short* __restrict__ hb, float* __restrict__ a_src_n, float* __restrict__ a_dst_n,
    const int* __restrict__ ei, int* __restrict__ hist2d, int* __restrict__ scannedT,
    int* __restrict__ bsum, int* __restrict__ off, unsigned* __restrict__ bucketed,
    int* __restrict__ csr,
    int N, int E, int Etot, int NBUCK, int NB, int Ntot, int NCH, int GB)
{
    extern __shared__ __align__(16) char smem[];
    cg::grid_group gg = cg::this_grid();
    const int t = threadIdx.x;
    const int NBLK = gridDim.x;

    // ---- Phase A ----
    for (int u = blockIdx.x; u < 128 + NB; u += NBLK) {
        __syncthreads();
        if (u < 128) {
            int id = u * 512 + t;
            int n = id >> 8, k = id & 255;
            Wt[id] = f2bf(W[k * 256 + n]);
            if (id == 0) off[N] = Etot;
        } else {
            int* lh = (int*)smem;
            const int cblk = u - 128;
            for (int b = t; b < NBUCK; b += 512) lh[b] = 0;
            __syncthreads();
            const int e0 = cblk * EPB;
            if (e0 + EPB <= E) {
                int e = e0 + t * 4;
                int4 d = *(const int4*)(ei + E + e);
                atomicAdd(&lh[d.x >> BSH], 1);
                atomicAdd(&lh[d.y >> BSH], 1);
                atomicAdd(&lh[d.z >> BSH], 1);
                atomicAdd(&lh[d.w >> BSH], 1);
            } else {
                for (int i = 0; i < EPB / 512; ++i) {
                    int e = e0 + i * 512 + t;
                    if (e < Etot) {
                        int dte = (e < E) ? ei[E + e] : (e - E);
                        atomicAdd(&lh[dte >> BSH], 1);
                    }
                }
            }
            __syncthreads();
            for (int b = t; b < NBUCK; b += 512) hist2d[b * NB + cblk] = lh[b];
        }
    }
    __threadfence();
    gg.sync();

    // ---- Phase B: scan || GEMM ----
    for (int u = blockIdx.x; u < NCH + GB; u += NBLK) {
        __syncthreads();
        if (u < NCH) {
            int* wsum = (int*)smem;
            int* wexc = (int*)smem + 8;
            const int lane = t & 63, w = t >> 6;
            int base = u << 10;
            int i0 = base + 2 * t;
            int v0 = (i0 < Ntot) ? hist2d[i0] : 0;
            int v1 = (i0 + 1 < Ntot) ? hist2d[i0 + 1] : 0;
            int pv = v0 + v1;
            int val = pv;
#pragma unroll
            for (int o = 1; o < 64; o <<= 1) { int s2 = __shfl_up(val, o); if (lane >= o) val += s2; }
            if (lane == 63) wsum[w] = val;
            __syncthreads();
            if (t < 8) {
                int s = wsum[t];
#pragma unroll
                for (int o = 1; o < 8; o <<= 1) { int s2 = __shfl_up(s, o, 8); if (t >= o) s += s2; }
                wexc[t] = s - wsum[t];
                if (t == 7) bsum[u] = s;
            }
            __syncthreads();
            int excl = wexc[w] + val - pv;
            if (i0 < Ntot) { int b = i0 / NB, cb = i0 - b * NB; scannedT[(size_t)cb * NBUCK + b] = excl; }
            if (i0 + 1 < Ntot) { int idx = i0 + 1; int b = idx / NB, cb = idx - b * NB; scannedT[(size_t)cb * NBUCK + b] = excl + v0; }
        } else {
            gemm_body(smem, t, (u - NCH) * 128, x, Wt, att_src, att_dst,
                      hb, a_src_n, a_dst_n, N);
        }
    }
    __threadfence();
    gg.sync();

    // ---- Phase C: scatter ----
    for (int u = blockIdx.x; u < NB; u += NBLK) {
        __syncthreads();
        scatter_body(smem, t, u, ei, scannedT, bsum, bucketed, E, N, NBUCK, NB, NCH);
    }
    __threadfence();
    gg.sync();

    // ---- Phase D: csr_build ----
    for (int u = blockIdx.x; u < NBUCK; u += NBLK) {
        __syncthreads();
        csr_body(smem, t, u, bucketed, scannedT, bsum, off, csr, N, NB, NBUCK, Etot, NCH);
    }
}

// ---------------------------------------------------------------------------
// FALLBACK kernels (R13 path) — used only if cooperative launch fails.
// ---------------------------------------------------------------------------
__global__ __launch_bounds__(256) void prep_count(
    const float* __restrict__ W, short* __restrict__ Wt, int* __restrict__ off,
    const int* __restrict__ ei, int* __restrict__ hist2d,
    int E, int N, int NBUCK, int NB, int Etot)
{
    const int blk = blockIdx.x, t = threadIdx.x;
    if (blk < 256) {
        int id = blk * 256 + t;
        int n = id >> 8, k = id & 255;
        Wt[id] = f2bf(W[k * 256 + n]);
        if (id == 0) off[N] = Etot;
        return;
    }
    extern __shared__ int lh[];
    const int cblk = blk - 256;
    for (int b = t; b < NBUCK; b += 256) lh[b] = 0;
    __syncthreads();
    const int e0 = cblk * EPB;
    if (e0 + EPB <= E) {
#pragma unroll
        for (int i = 0; i < EPB / 1024; ++i) {
            int e = e0 + i * 1024 + t * 4;
            int4 d = *(const int4*)(ei + E + e);
            atomicAdd(&lh[d.x >> BSH], 1);
            atomicAdd(&lh[d.y >> BSH], 1);
            atomicAdd(&lh[d.z >> BSH], 1);
            atomicAdd(&lh[d.w >> BSH], 1);
        }
    } else {
        for (int i = 0; i < EPB / 256; ++i) {
            int e = e0 + i * 256 + t;
            if (e < Etot) {
                int dte = (e < E) ? ei[E + e] : (e - E);
                atomicAdd(&lh[dte >> BSH], 1);
            }
        }
    }
    __syncthreads();
    for (int b = t; b < NBUCK; b += 256) hist2d[b * NB + cblk] = lh[b];
}

__global__ __launch_bounds__(1024) void scan1(const int* __restrict__ src,
                                              int* __restrict__ dstT,
                                              int* __restrict__ bsum,
                                              int Ntot, int NB, int NBUCK)
{
    __shared__ int wsum[16], wexc[16];
    const int t = threadIdx.x, lane = t & 63, w = t >> 6;
    const int idx = blockIdx.x * 1024 + t;
    int v = (idx < Ntot) ? src[idx] : 0;
    int val = v;
#pragma unroll
    for (int o = 1; o < 64; o <<= 1) {
        int u = __shfl_up(val, o);
        if (lane >= o) val += u;
    }
    if (lane == 63) wsum[w] = val;
    __syncthreads();
    if (t < 16) {
        int s = wsum[t];
#pragma unroll
        for (int o = 1; o < 16; o <<= 1) {
            int u = __shfl_up(s, o, 16);
            if (t >= o) s += u;
        }
        wexc[t] = s - wsum[t];
        if (t == 15) bsum[blockIdx.x] = s;
    }
    __syncthreads();
    if (idx < Ntot) {
        int b = idx / NB, cblk = idx - b * NB;
        dstT[(size_t)cblk * NBUCK + b] = wexc[w] + val - v;
    }
}

__global__ __launch_bounds__(512) void gemm_scatter(
    const float* __restrict__ x, const short* __restrict__ Wt,
    const float* __restrict__ att_src, const float* __restrict__ att_dst,
    short* __restrict__ hb, float* __restrict__ a_src_n,
    float* __restrict__ a_dst_n, int M, int GB,
    const int* __restrict__ ei, const int* __restrict__ scannedT,
    const int* __restrict__ bsum, unsigned* __restrict__ bucketed,
    int E, int N, int NBUCK, int NB, int NCH)
{
    extern __shared__ __align__(16) char smem2[];
    const int t = threadIdx.x;
    if (blockIdx.x >= GB) {
        scatter_body(smem2, t, blockIdx.x - GB, ei, scannedT, bsum, bucketed,
                     E, N, NBUCK, NB, NCH);
        return;
    }
    gemm_body(smem2, t, blockIdx.x * 128, x, Wt, att_src, att_dst,
              hb, a_src_n, a_dst_n, M);
}

__global__ __launch_bounds__(512) void csr_build(
    const unsigned* __restrict__ bucketed, const int* __restrict__ scannedT,
    const int* __restrict__ bsum, int* __restrict__ off, int* __restrict__ csr,
    int N, int NB, int NBUCK, int Etot, int NCH)
{
    extern __shared__ __align__(16) char smem3[];
    csr_body(smem3, threadIdx.x, blockIdx.x, bucketed, scannedT, bsum, off, csr,
             N, NB, NBUCK, Etot, NCH);
}

// ---------------------------------------------------------------------------
// aggregate — PROVEN form (gather floor), single launch. FROZEN.
// ---------------------------------------------------------------------------
__global__ __launch_bounds__(256) void aggregate(const short* __restrict__ hb,
                                                 const float* __restrict__ a_src_n,
                                                 const float* __restrict__ a_dst_n,
                                                 const int* __restrict__ off,
                                                 const int* __restrict__ csr,
                                                 const float* __restrict__ bias,
                                                 float* __restrict__ out, int N)
{
    __shared__ float lds_w[4][64][4];
    __shared__ int   lds_s[4][64];
    const int wv = threadIdx.x >> 6;
    const int lane = threadIdx.x & 63;
    const int half = lane >> 5, l31 = lane & 31;
    const int n = blockIdx.x * 4 + wv;
    if (n >= N) return;

    const int base = off[n];
    const int d = off[n + 1] - base;
    const float4 ad = *(const float4*)(a_dst_n + 4 * n);
    const int hl = l31 >> 3;

    float acc[8] = {0.f, 0.f, 0.f, 0.f, 0.f, 0.f, 0.f, 0.f};
    float4 sum = make_float4(0.f, 0.f, 0.f, 0.f);
    const uint4* hp = (const uint4*)hb;

    for (int c0 = 0; c0 < d; c0 += 64) {
        int j = c0 + lane;
        int s = 0;
        float4 w4 = make_float4(0.f, 0.f, 0.f, 0.f);
        if (j < d) {
            s = csr[base + j];
            float4 as = *(const float4*)(a_src_n + 4 * s);
            float lx = as.x + ad.x; lx = lx >= 0.f ? lx : NEG * lx;
            float ly = as.y + ad.y; ly = ly >= 0.f ? ly : NEG * ly;
            float lz = as.z + ad.z; lz = lz >= 0.f ? lz : NEG * lz;
            float lw = as.w + ad.w; lw = lw >= 0.f ? lw : NEG * lw;
            w4 = make_float4(__expf(lx), __expf(ly), __expf(lz), __expf(lw));
        }
        sum.x += w4.x; sum.y += w4.y; sum.z += w4.z; sum.w += w4.w;
        *(float4*)&lds_w[wv][lane][0] = w4;
        lds_s[wv][lane] = s;
        __builtin_amdgcn_wave_barrier();

        const int cl = (d - c0) < 64 ? (d - c0) : 64;
        int jj = 0;
        for (; jj + 4 <= cl; jj += 4) {
            int   s0 = lds_s[wv][jj + half];
            int   s1 = lds_s[wv][jj + 2 + half];
            float w0 = lds_w[wv][jj + half][hl];
            float w1 = lds_w[wv][jj + 2 + half][hl];
            uint4 v0 = hp[(size_t)s0 * 32 + l31];
            uint4 v1 = hp[(size_t)s1 * 32 + l31];
            acc[0] = fmaf(w0, bf2f((unsigned short)(v0.x & 0xffff)), acc[0]);
            acc[1] = fmaf(w0, bf2f((unsigned short)(v0.x >> 16)),    acc[1]);
            acc[2] = fmaf(w0, bf2f((unsigned short)(v0.y & 0xffff)), acc[2]);
            acc[3] = fmaf(w0, bf2f((unsigned short)(v0.y >> 16)),    acc[3]);
            acc[4] = fmaf(w0, bf2f((unsigned short)(v0.z & 0xffff)), acc[4]);
            acc[5] = fmaf(w0, bf2f((unsigned short)(v0.z >> 16)),    acc[5]);
            acc[6] = fmaf(w0, bf2f((unsigned short)(v0.w & 0xffff)), acc[6]);
            acc[7] = fmaf(w0, bf2f((unsigned short)(v0.w >> 16)),    acc[7]);
            acc[0] = fmaf(w1, bf2f((unsigned short)(v1.x & 0xffff)), acc[0]);
            acc[1] = fmaf(w1, bf2f((unsigned short)(v1.x >> 16)),    acc[1]);
            acc[2] = fmaf(w1, bf2f((unsigned short)(v1.y & 0xffff)), acc[2]);
            acc[3] = fmaf(w1, bf2f((unsigned short)(v1.y >> 16)),    acc[3]);
            acc[4] = fmaf(w1, bf2f((unsigned short)(v1.z & 0xffff)), acc[4]);
            acc[5] = fmaf(w1, bf2f((unsigned short)(v1.z >> 16)),    acc[5]);
            acc[6] = fmaf(w1, bf2f((unsigned short)(v1.w & 0xffff)), acc[6]);
            acc[7] = fmaf(w1, bf2f((unsigned short)(v1.w >> 16)),    acc[7]);
        }
        for (; jj < cl; jj += 2) {
            int   s0 = lds_s[wv][jj + half];
            float w0 = lds_w[wv][jj + half][hl];
            uint4 v0 = hp[(size_t)s0 * 32 + l31];
            acc[0] = fmaf(w0, bf2f((unsigned short)(v0.x & 0xffff)), acc[0]);
            acc[1] = fmaf(w0, bf2f((unsigned short)(v0.x >> 16)),    acc[1]);
            acc[2] = fmaf(w0, bf2f((unsigned short)(v0.y & 0xffff)), acc[2]);
            acc[3] = fmaf(w0, bf2f((unsigned short)(v0.y >> 16)),    acc[3]);
            acc[4] = fmaf(w0, bf2f((unsigned short)(v0.z & 0xffff)), acc[4]);
            acc[5] = fmaf(w0, bf2f((unsigned short)(v0.z >> 16)),    acc[5]);
            acc[6] = fmaf(w0, bf2f((unsigned short)(v0.w & 0xffff)), acc[6]);
            acc[7] = fmaf(w0, bf2f((unsigned short)(v0.w >> 16)),    acc[7]);
        }
        __builtin_amdgcn_wave_barrier();
    }

#pragma unroll
    for (int k = 0; k < 8; ++k) acc[k] += __shfl_xor(acc[k], 32);

#pragma unroll
    for (int o = 32; o > 0; o >>= 1) {
        sum.x += __shfl_xor(sum.x, o);
        sum.y += __shfl_xor(sum.y, o);
        sum.z += __shfl_xor(sum.z, o);
        sum.w += __shfl_xor(sum.w, o);
    }
    float sh = (hl & 2) ? ((hl & 1) ? sum.w : sum.z) : ((hl & 1) ? sum.y : sum.x);
    float ih = 1.f / (sh + 1e-16f);

    if (half == 0) {
        const float4* bp = (const float4*)bias + l31 * 2;
        float4 b0 = bp[0], b1 = bp[1];
        float4 o0, o1;
        o0.x = fmaxf(fmaf(acc[0], ih, b0.x), 0.f);
        o0.y = fmaxf(fmaf(acc[1], ih, b0.y), 0.f);
        o0.z = fmaxf(fmaf(acc[2], ih, b0.z), 0.f);
        o0.w = fmaxf(fmaf(acc[3], ih, b0.w), 0.f);
        o1.x = fmaxf(fmaf(acc[4], ih, b1.x), 0.f);
        o1.y = fmaxf(fmaf(acc[5], ih, b1.y), 0.f);
        o1.z = fmaxf(fmaf(acc[6], ih, b1.z), 0.f);
        o1.w = fmaxf(fmaf(acc[7], ih, b1.w), 0.f);
        float4* op = (float4*)(out + (size_t)n * 256) + l31 * 2;
        op[0] = o0;
        op[1] = o1;
    }
}

// ---------------------------------------------------------------------------
extern "C" void kernel_launch(void* const* d_in, const int* in_sizes, int n_in,
                              void* d_out, int out_size, void* d_ws, size_t ws_size,
                              hipStream_t stream)
{
    const float* x       = (const float*)d_in[0];
    const int*   ei      = (const int*)d_in[1];
    const float* W       = (const float*)d_in[2];
    const float* att_src = (const float*)d_in[3];
    const float* att_dst = (const float*)d_in[4];
    const float* bias    = (const float*)d_in[5];
    float* out = (float*)d_out;

    const int N = in_sizes[0] / 256;       // 50000
    const int E = in_sizes[1] / 2;         // 800000
    const int Etot = E + N;                // 850000
    const int NBUCK = (N + 63) >> BSH;     // 782
    const int NB = (Etot + EPB - 1) / EPB; // 416
    const int Ntot = NBUCK * NB;           // ~325k
    const int NCH = (Ntot + 1023) / 1024;  // 318 scan chunks
    const int GB = (N + 127) / 128;        // 391 gemm blocks

    // workspace carve (~37 MB; ws >= 56 MB)
    char* p = (char*)d_ws;
    short*    hb      = (short*)p;    p += (size_t)N * 256 * sizeof(short);
    short*    Wt      = (short*)p;    p += 256 * 256 * sizeof(short);
    float*    a_src_n = (float*)p;    p += (size_t)N * 4 * sizeof(float);
    float*    a_dst_n = (float*)p;    p += (size_t)N * 4 * sizeof(float);
    int*      hist2d  = (int*)p;      p += (size_t)Ntot * sizeof(int);
    int*      scannedT= (int*)p;      p += (size_t)Ntot * sizeof(int);
    int*      bsum    = (int*)p;      p += 1024 * sizeof(int);
    int*      off     = (int*)p;      p += (size_t)(N + 1) * sizeof(int);
    unsigned* bucketed= (unsigned*)p; p += (size_t)Etot * sizeof(unsigned);
    int*      csr     = (int*)p;      p += (size_t)Etot * sizeof(int);

    // cooperative grid size (cached): co-resident blocks only
    static int s_coopGrid = -1;
    if (s_coopGrid < 0) {
        int nb = 0;
        hipError_t qe = hipOccupancyMaxActiveBlocksPerMultiprocessor(&nb, mega, 512,
                                                                     (size_t)16384);
        if (qe != hipSuccess || nb < 1) nb = 1;
        int g = nb * 256;                  // 256 CUs on MI355X
        if (g > NBUCK) g = NBUCK;          // max phase units = 782
        s_coopGrid = g;
    }

    const float* x_ = x; const float* W_ = W; short* Wt_ = Wt;
    const float* as_ = att_src; const float* ad_ = att_dst;
    short* hb_ = hb; float* asn_ = a_src_n; float* adn_ = a_dst_n;
    const int* ei_ = ei; int* h2_ = hist2d; int* sT_ = scannedT;
    int* bs_ = bsum; int* off_ = off; unsigned* bk_ = bucketed; int* csr_ = csr;
    int N_ = N, E_ = E, Etot_ = Etot, NBUCK_ = NBUCK, NB_ = NB,
        Ntot_ = Ntot, NCH_ = NCH, GB_ = GB;
    void* margs[] = { &x_, &W_, &Wt_, &as_, &ad_, &hb_, &asn_, &adn_, &ei_,
                      &h2_, &sT_, &bs_, &off_, &bk_, &csr_,
                      &N_, &E_, &Etot_, &NBUCK_, &NB_, &Ntot_, &NCH_, &GB_ };

    hipError_t ce = hipLaunchCooperativeKernel(mega, dim3(s_coopGrid), dim3(512),
                                               margs, 16384, stream);
    if (ce != hipSuccess) {
        // fallback: proven R13 multi-kernel path
        (void)hipGetLastError();           // clear sticky error
        prep_count<<<256 + NB, 256, NBUCK * sizeof(int), stream>>>(
            W, Wt, off, ei, hist2d, E, N, NBUCK, NB, Etot);
        scan1<<<NCH, 1024, 0, stream>>>(hist2d, scannedT, bsum, Ntot, NB, NBUCK);
        gemm_scatter<<<GB + NB, 512, 16384, stream>>>(
            x, Wt, att_src, att_dst, hb, a_src_n, a_dst_n, N, GB,
            ei, scannedT, bsum, bucketed, E, N, NBUCK, NB, NCH);
        csr_build<<<NBUCK, 512, 16384, stream>>>(bucketed, scannedT, bsum, off, csr,
                                                 N, NB, NBUCK, Etot, NCH);
    }
    aggregate<<<(N + 3) / 4, 256, 0, stream>>>(hb, a_src_n, a_dst_n, off, csr,
                                               bias, out, N);
}

// Round 15
// 213.278 us; speedup vs baseline: 2.5160x; 2.5160x over previous
//
#include <hip/hip_runtime.h>
#include <hip/hip_bf16.h>
#include <math.h>

#define NEG 0.2f
#define BSH 6                 // bucket = dst >> 6  (64 dsts per bucket)
#define EPB 4096              // edges per hist/scatter block (208 blocks)

typedef __attribute__((ext_vector_type(4))) float f4;
typedef __attribute__((ext_vector_type(8))) short s8;

__device__ __forceinline__ short f2bf(float f) {
    unsigned u = __float_as_uint(f);
    u += 0x7fff + ((u >> 16) & 1);          // round-to-nearest-even
    return (short)(u >> 16);
}
__device__ __forceinline__ unsigned pk2(float a, float b) {
    union { __hip_bfloat162 h; unsigned u; } c;
    c.h = __float22bfloat162_rn(make_float2(a, b));   // v_cvt_pk_bf16_f32
    return c.u;
}
__device__ __forceinline__ float bf2f(unsigned short s) {
    return __uint_as_float(((unsigned)s) << 16);
}

// ---------------------------------------------------------------------------
// Kernel 0: prep_count — blocks [0,256): Wt[n][k]=bf16(W[k][n]) + off[N];
// blocks [256, 256+NB): 2D bucket histogram hist2d[bucket][blk]
// (no global atomics; int4 edge loads on the fast path).
// ---------------------------------------------------------------------------
__global__ __launch_bounds__(256) void prep_count(
    const float* __restrict__ W, short* __restrict__ Wt, int* __restrict__ off,
    const int* __restrict__ ei, int* __restrict__ hist2d,
    int E, int N, int NBUCK, int NB, int Etot)
{
    const int blk = blockIdx.x, t = threadIdx.x;
    if (blk < 256) {
        int id = blk * 256 + t;
        int n = id >> 8, k = id & 255;
        Wt[id] = f2bf(W[k * 256 + n]);
        if (id == 0) off[N] = Etot;
        return;
    }
    extern __shared__ int lh[];           // NBUCK ints
    const int cblk = blk - 256;
    for (int b = t; b < NBUCK; b += 256) lh[b] = 0;
    __syncthreads();
    const int e0 = cblk * EPB;
    if (e0 + EPB <= E) {                  // fast path: int4 dst loads
#pragma unroll
        for (int i = 0; i < EPB / 1024; ++i) {
            int e = e0 + i * 1024 + t * 4;
            int4 d = *(const int4*)(ei + E + e);
            atomicAdd(&lh[d.x >> BSH], 1);
            atomicAdd(&lh[d.y >> BSH], 1);
            atomicAdd(&lh[d.z >> BSH], 1);
            atomicAdd(&lh[d.w >> BSH], 1);
        }
    } else {                              // boundary / self-loop blocks
        for (int i = 0; i < EPB / 256; ++i) {
            int e = e0 + i * 256 + t;
            if (e < Etot) {
                int dte = (e < E) ? ei[E + e] : (e - E);
                atomicAdd(&lh[dte >> BSH], 1);
            }
        }
    }
    __syncthreads();
    for (int b = t; b < NBUCK; b += 256) hist2d[b * NB + cblk] = lh[b];
}

// ---------------------------------------------------------------------------
// Kernel 1: scan1 — per-1024-chunk exclusive scan of hist2d (Ntot elems) +
// chunk totals bsum. Consumers recompute the chunk-exclusive offsets (bexc)
// from bsum locally — no scan2v launch.
// ---------------------------------------------------------------------------
__global__ __launch_bounds__(1024) void scan1(const int* __restrict__ src,
                                              int* __restrict__ dst,
                                              int* __restrict__ bsum, int Ntot)
{
    __shared__ int wsum[16], wexc[16];
    const int t = threadIdx.x, lane = t & 63, w = t >> 6;
    const int idx = blockIdx.x * 1024 + t;
    int v = (idx < Ntot) ? src[idx] : 0;
    int val = v;
#pragma unroll
    for (int o = 1; o < 64; o <<= 1) {
        int u = __shfl_up(val, o);
        if (lane >= o) val += u;
    }
    if (lane == 63) wsum[w] = val;
    __syncthreads();
    if (t < 16) {
        int s = wsum[t];
#pragma unroll
        for (int o = 1; o < 16; o <<= 1) {
            int u = __shfl_up(s, o, 16);
            if (t >= o) s += u;
        }
        wexc[t] = s - wsum[t];
        if (t == 15) bsum[blockIdx.x] = s;
    }
    __syncthreads();
    if (idx < Ntot) dst[idx] = wexc[w] + val - v;
}

// ---------------------------------------------------------------------------
// helper: one WAVE (lanes t<64) computes the exclusive scan of bsum[0..NCH)
// into bexc_l[] in LDS (NCH <= 192: 64-wide scan rounds with carry).
// ---------------------------------------------------------------------------
__device__ __forceinline__ void bexc_scan_wave(const int* __restrict__ bsum,
                                               int* bexc_l, int NCH, int t)
{
    if (t < 64) {
        int carry = 0;
        for (int base = 0; base < NCH; base += 64) {
            int i = base + t;
            int v = (i < NCH) ? bsum[i] : 0;
            int val = v;
#pragma unroll
            for (int o = 1; o < 64; o <<= 1) {
                int u = __shfl_up(val, o);
                if (t >= o) val += u;
            }
            if (i < NCH) bexc_l[i] = carry + val - v;
            carry += __shfl(val, 63);
        }
    }
}

// ---------------------------------------------------------------------------
// Kernel 2: gemm_scatter — FUSED launch of two INDEPENDENT stages:
//  blocks [0, GB):       MFMA GEMM (needs x, Wt — ready after prep_count)
//  blocks [GB, GB+NB):   bucket scatter, LDS cursors (bexc computed in-block)
// ---------------------------------------------------------------------------
__global__ __launch_bounds__(512) void gemm_scatter(
    const float* __restrict__ x, const short* __restrict__ Wt,
    const float* __restrict__ att_src, const float* __restrict__ att_dst,
    short* __restrict__ hb, float* __restrict__ a_src_n,
    float* __restrict__ a_dst_n, int M, int GB,
    const int* __restrict__ ei, const int* __restrict__ scanned,
    const int* __restrict__ bsum, unsigned* __restrict__ bucketed,
    int E, int N, int NBUCK, int NB, int NCH)
{
    extern __shared__ __align__(16) char smem[];   // 16 KB: xs OR bexc+lcur
    const int t = threadIdx.x;

    if (blockIdx.x >= GB) {
        // ---------------- scatter part (512 threads) ----------------
        int* bexc_l = (int*)smem;                  // 256 ints reserved
        int* lcur   = (int*)smem + 256;            // NBUCK ints
        const int cblk = blockIdx.x - GB;
        bexc_scan_wave(bsum, bexc_l, NCH, t);
        __syncthreads();
        for (int b = t; b < NBUCK; b += 512) {
            int idx = b * NB + cblk;
            lcur[b] = scanned[idx] + bexc_l[idx >> 10];
        }
        __syncthreads();
        const int e0 = cblk * EPB, Etot = E + N;
        if (e0 + EPB <= E) {                       // fast path: int4 loads
#pragma unroll
            for (int i = 0; i < EPB / 2048; ++i) {
                int e = e0 + i * 2048 + t * 4;
                int4 s4 = *(const int4*)(ei + e);
                int4 d4 = *(const int4*)(ei + E + e);
                int p0 = atomicAdd(&lcur[d4.x >> BSH], 1);
                bucketed[p0] = (unsigned)s4.x | ((unsigned)(d4.x & 63) << 20);
                int p1 = atomicAdd(&lcur[d4.y >> BSH], 1);
                bucketed[p1] = (unsigned)s4.y | ((unsigned)(d4.y & 63) << 20);
                int p2 = atomicAdd(&lcur[d4.z >> BSH], 1);
                bucketed[p2] = (unsigned)s4.z | ((unsigned)(d4.z & 63) << 20);
                int p3 = atomicAdd(&lcur[d4.w >> BSH], 1);
                bucketed[p3] = (unsigned)s4.w | ((unsigned)(d4.w & 63) << 20);
            }
        } else {
            for (int i = 0; i < EPB / 512; ++i) {
                int e = e0 + i * 512 + t;
                if (e < Etot) {
                    int src, dte;
                    if (e < E) { src = ei[e]; dte = ei[E + e]; }
                    else       { src = e - E; dte = src; }
                    int pos = atomicAdd(&lcur[dte >> BSH], 1);
                    bucketed[pos] = (unsigned)src | ((unsigned)(dte & 63) << 20);
                }
            }
        }
        return;
    }

    // ---------------- GEMM part (8 waves, 128 nodes x 256 ch) ----------------
    short (*xs)[128][32] = (short (*)[128][32])smem;   // [2][128][32] dbuf
    const int lane = t & 63, wv = t >> 6;
    const int wr = wv >> 2;                       // node half
    const int hd = wv & 3;                        // head (64 channels)
    const int quad = lane >> 4, l15 = lane & 15;
    const int n0 = blockIdx.x * 128;

    const int row = t >> 2, kq = t & 3;           // 512 threads cover 128x32
    const bool okr = (n0 + row) < M;
    const float* xp = x + (size_t)(n0 + row) * 256 + kq * 8;

    const short* wbase = Wt + (size_t)(hd * 64 + l15) * 256 + quad * 8;

    f4 acc[4][4];   // [i: ch frag][j: node frag]
#pragma unroll
    for (int i = 0; i < 4; ++i)
#pragma unroll
        for (int j = 0; j < 4; ++j) acc[i][j] = (f4)(0.f);

    float4 v0 = {}, v1 = {};
    if (okr) { const float4* p = (const float4*)xp; v0 = p[0]; v1 = p[1]; }

    // prime the af pipeline (no barrier dependence — issues immediately)
    s8 af[4];
#pragma unroll
    for (int i = 0; i < 4; ++i)
        af[i] = *(const s8*)(wbase + (size_t)(i * 16) * 256);

    int buf = 0;
#pragma unroll
    for (int ks = 0; ks < 8; ++ks) {
        uint4 u = { pk2(v0.x, v0.y), pk2(v0.z, v0.w), pk2(v1.x, v1.y), pk2(v1.z, v1.w) };
        *(uint4*)&xs[buf][row][kq * 8] = u;
        __syncthreads();

        if (ks < 7 && okr) {              // prefetch next k-step x (overlaps MFMA)
            const float4* p = (const float4*)(xp + (ks + 1) * 32);
            v0 = p[0]; v1 = p[1];
        }

        s8 afn[4];
        if (ks < 7) {                     // prefetch next k-step Wt (overlaps MFMA)
#pragma unroll
            for (int i = 0; i < 4; ++i)
                afn[i] = *(const s8*)(wbase + (size_t)(i * 16) * 256 + (ks + 1) * 32);
        }

        s8 bf[4];
#pragma unroll
        for (int j = 0; j < 4; ++j)
            bf[j] = *(const s8*)&xs[buf][wr * 64 + j * 16 + l15][quad * 8];
#pragma unroll
        for (int i = 0; i < 4; ++i)
#pragma unroll
            for (int j = 0; j < 4; ++j)
                acc[i][j] = __builtin_amdgcn_mfma_f32_16x16x32_bf16(af[i], bf[j], acc[i][j], 0, 0, 0);

        if (ks < 7) {
#pragma unroll
            for (int i = 0; i < 4; ++i) af[i] = afn[i];
        }
        buf ^= 1;
    }

    float asv[4][4], adv[4][4];
#pragma unroll
    for (int i = 0; i < 4; ++i)
#pragma unroll
        for (int rr = 0; rr < 4; ++rr) {
            asv[i][rr] = att_src[hd * 64 + i * 16 + quad * 4 + rr];
            adv[i][rr] = att_dst[hd * 64 + i * 16 + quad * 4 + rr];
        }

#pragma unroll
    for (int j = 0; j < 4; ++j) {
        const int node = n0 + wr * 64 + j * 16 + l15;
        const bool ok = node < M;
        float ps = 0.f, pd = 0.f;
#pragma unroll
        for (int i = 0; i < 4; ++i)
#pragma unroll
            for (int rr = 0; rr < 4; ++rr) {
                float v = acc[i][j][rr];
                ps = fmaf(v, asv[i][rr], ps);
                pd = fmaf(v, adv[i][rr], pd);
            }
        ps += __shfl_xor(ps, 16); ps += __shfl_xor(ps, 32);
        pd += __shfl_xor(pd, 16); pd += __shfl_xor(pd, 32);
        if (ok && quad == 0) {
            a_src_n[node * 4 + hd] = ps;
            a_dst_n[node * 4 + hd] = pd;
        }
        if (ok) {
#pragma unroll
            for (int i = 0; i < 4; ++i) {
                uint2 pk = make_uint2(pk2(acc[i][j][0], acc[i][j][1]),
                                      pk2(acc[i][j][2], acc[i][j][3]));
                *(uint2*)&hb[(size_t)node * 256 + hd * 64 + i * 16 + quad * 4] = pk;
            }
        }
    }
}

// ---------------------------------------------------------------------------
// Kernel 3: csr_build — one block per bucket (64 dsts): group entries by dst
// into global csr (dst-sorted) + off[n]. bexc recomputed in-block from bsum.
// ---------------------------------------------------------------------------
__global__ __launch_bounds__(256) void csr_build(
    const unsigned* __restrict__ bucketed, const int* __restrict__ scanned,
    const int* __restrict__ bsum, int* __restrict__ off, int* __restrict__ csr,
    int N, int NB, int NBUCK, int Etot, int NCH)
{
    __shared__ unsigned est[2048];
    __shared__ int ldeg4[4][64], lcur4[4][64], loff[64], bexc_l[192];
    const int t = threadIdx.x, wv = t >> 6, b = blockIdx.x;

    bexc_scan_wave(bsum, bexc_l, NCH, t);
    ldeg4[t >> 6][t & 63] = 0;             // 256 threads zero 4x64 exactly
    __syncthreads();

    const int i0 = b * NB;
    const int gbase = scanned[i0] + bexc_l[i0 >> 10];
    int gend;
    if (b + 1 == NBUCK) gend = Etot;
    else { int i1 = (b + 1) * NB; gend = scanned[i1] + bexc_l[i1 >> 10]; }
    int cnt = gend - gbase;
    if (cnt > 2048) cnt = 2048;            // never hit (~1090 avg, max ~1300)

    for (int i = t; i < cnt; i += 256) {
        unsigned en = bucketed[gbase + i];
        est[i] = en;
        atomicAdd(&ldeg4[wv][en >> 20], 1);
    }
    __syncthreads();
    if (t < 64) {                          // single wave: 64-wide scan
        int d0 = ldeg4[0][t], d1 = ldeg4[1][t], d2 = ldeg4[2][t], d3 = ldeg4[3][t];
        int tot = d0 + d1 + d2 + d3;
        int val = tot;
#pragma unroll
        for (int o = 1; o < 64; o <<= 1) {
            int u = __shfl_up(val, o);
            if (t >= o) val += u;
        }
        int excl = val - tot;
        loff[t] = excl;
        lcur4[0][t] = excl;
        lcur4[1][t] = excl + d0;
        lcur4[2][t] = excl + d0 + d1;
        lcur4[3][t] = excl + d0 + d1 + d2;
    }
    __syncthreads();
    for (int i = t; i < cnt; i += 256) {
        unsigned en = est[i];
        int pos = atomicAdd(&lcur4[wv][en >> 20], 1);
        csr[gbase + pos] = (int)(en & 0xFFFFF);
    }
    if (t < 64) {
        int n = (b << BSH) + t;
        if (n < N) off[n] = gbase + loff[t];
    }
}

// ---------------------------------------------------------------------------
// Kernel 4: aggregate — PROVEN form (gather floor), single launch. FROZEN.
// ---------------------------------------------------------------------------
__global__ __launch_bounds__(256) void aggregate(const short* __restrict__ hb,
                                                 const float* __restrict__ a_src_n,
                                                 const float* __restrict__ a_dst_n,
                                                 const int* __restrict__ off,
                                                 const int* __restrict__ csr,
                                                 const float* __restrict__ bias,
                                                 float* __restrict__ out, int N)
{
    __shared__ float lds_w[4][64][4];
    __shared__ int   lds_s[4][64];
    const int wv = threadIdx.x >> 6;
    const int lane = threadIdx.x & 63;
    const int half = lane >> 5, l31 = lane & 31;
    const int n = blockIdx.x * 4 + wv;
    if (n >= N) return;

    const int base = off[n];
    const int d = off[n + 1] - base;
    const float4 ad = *(const float4*)(a_dst_n + 4 * n);
    const int hl = l31 >> 3;             // head of this lane's 8 channels

    float acc[8] = {0.f, 0.f, 0.f, 0.f, 0.f, 0.f, 0.f, 0.f};
    float4 sum = make_float4(0.f, 0.f, 0.f, 0.f);
    const uint4* hp = (const uint4*)hb;

    for (int c0 = 0; c0 < d; c0 += 64) {
        int j = c0 + lane;
        int s = 0;
        float4 w4 = make_float4(0.f, 0.f, 0.f, 0.f);
        if (j < d) {
            s = csr[base + j];
            float4 as = *(const float4*)(a_src_n + 4 * s);
            float lx = as.x + ad.x; lx = lx >= 0.f ? lx : NEG * lx;
            float ly = as.y + ad.y; ly = ly >= 0.f ? ly : NEG * ly;
            float lz = as.z + ad.z; lz = lz >= 0.f ? lz : NEG * lz;
            float lw = as.w + ad.w; lw = lw >= 0.f ? lw : NEG * lw;
            w4 = make_float4(__expf(lx), __expf(ly), __expf(lz), __expf(lw));
        }
        sum.x += w4.x; sum.y += w4.y; sum.z += w4.z; sum.w += w4.w;
        *(float4*)&lds_w[wv][lane][0] = w4;
        lds_s[wv][lane] = s;
        __builtin_amdgcn_wave_barrier();

        const int cl = (d - c0) < 64 ? (d - c0) : 64;
        int jj = 0;
        for (; jj + 4 <= cl; jj += 4) {
            int   s0 = lds_s[wv][jj + half];
            int   s1 = lds_s[wv][jj + 2 + half];
            float w0 = lds_w[wv][jj + half][hl];
            float w1 = lds_w[wv][jj + 2 + half][hl];
            uint4 v0 = hp[(size_t)s0 * 32 + l31];
            uint4 v1 = hp[(size_t)s1 * 32 + l31];
            acc[0] = fmaf(w0, bf2f((unsigned short)(v0.x & 0xffff)), acc[0]);
            acc[1] = fmaf(w0, bf2f((unsigned short)(v0.x >> 16)),    acc[1]);
            acc[2] = fmaf(w0, bf2f((unsigned short)(v0.y & 0xffff)), acc[2]);
            acc[3] = fmaf(w0, bf2f((unsigned short)(v0.y >> 16)),    acc[3]);
            acc[4] = fmaf(w0, bf2f((unsigned short)(v0.z & 0xffff)), acc[4]);
            acc[5] = fmaf(w0, bf2f((unsigned short)(v0.z >> 16)),    acc[5]);
            acc[6] = fmaf(w0, bf2f((unsigned short)(v0.w & 0xffff)), acc[6]);
            acc[7] = fmaf(w0, bf2f((unsigned short)(v0.w >> 16)),    acc[7]);
            acc[0] = fmaf(w1, bf2f((unsigned short)(v1.x & 0xffff)), acc[0]);
            acc[1] = fmaf(w1, bf2f((unsigned short)(v1.x >> 16)),    acc[1]);
            acc[2] = fmaf(w1, bf2f((unsigned short)(v1.y & 0xffff)), acc[2]);
            acc[3] = fmaf(w1, bf2f((unsigned short)(v1.y >> 16)),    acc[3]);
            acc[4] = fmaf(w1, bf2f((unsigned short)(v1.z & 0xffff)), acc[4]);
            acc[5] = fmaf(w1, bf2f((unsigned short)(v1.z >> 16)),    acc[5]);
            acc[6] = fmaf(w1, bf2f((unsigned short)(v1.w & 0xffff)), acc[6]);
            acc[7] = fmaf(w1, bf2f((unsigned short)(v1.w >> 16)),    acc[7]);
        }
        for (; jj < cl; jj += 2) {   // tail: lds_s/lds_w initialized for all 64
            int   s0 = lds_s[wv][jj + half];
            float w0 = lds_w[wv][jj + half][hl];
            uint4 v0 = hp[(size_t)s0 * 32 + l31];
            acc[0] = fmaf(w0, bf2f((unsigned short)(v0.x & 0xffff)), acc[0]);
            acc[1] = fmaf(w0, bf2f((unsigned short)(v0.x >> 16)),    acc[1]);
            acc[2] = fmaf(w0, bf2f((unsigned short)(v0.y & 0xffff)), acc[2]);
            acc[3] = fmaf(w0, bf2f((unsigned short)(v0.y >> 16)),    acc[3]);
            acc[4] = fmaf(w0, bf2f((unsigned short)(v0.z & 0xffff)), acc[4]);
            acc[5] = fmaf(w0, bf2f((unsigned short)(v0.z >> 16)),    acc[5]);
            acc[6] = fmaf(w0, bf2f((unsigned short)(v0.w & 0xffff)), acc[6]);
            acc[7] = fmaf(w0, bf2f((unsigned short)(v0.w >> 16)),    acc[7]);
        }
        __builtin_amdgcn_wave_barrier();
    }

#pragma unroll
    for (int k = 0; k < 8; ++k) acc[k] += __shfl_xor(acc[k], 32);

#pragma unroll
    for (int o = 32; o > 0; o >>= 1) {
        sum.x += __shfl_xor(sum.x, o);
        sum.y += __shfl_xor(sum.y, o);
        sum.z += __shfl_xor(sum.z, o);
        sum.w += __shfl_xor(sum.w, o);
    }
    float sh = (hl & 2) ? ((hl & 1) ? sum.w : sum.z) : ((hl & 1) ? sum.y : sum.x);
    float ih = 1.f / (sh + 1e-16f);

    if (half == 0) {
        const float4* bp = (const float4*)bias + l31 * 2;
        float4 b0 = bp[0], b1 = bp[1];
        float4 o0, o1;
        o0.x = fmaxf(fmaf(acc[0], ih, b0.x), 0.f);
        o0.y = fmaxf(fmaf(acc[1], ih, b0.y), 0.f);
        o0.z = fmaxf(fmaf(acc[2], ih, b0.z), 0.f);
        o0.w = fmaxf(fmaf(acc[3], ih, b0.w), 0.f);
        o1.x = fmaxf(fmaf(acc[4], ih, b1.x), 0.f);
        o1.y = fmaxf(fmaf(acc[5], ih, b1.y), 0.f);
        o1.z = fmaxf(fmaf(acc[6], ih, b1.z), 0.f);
        o1.w = fmaxf(fmaf(acc[7], ih, b1.w), 0.f);
        float4* op = (float4*)(out + (size_t)n * 256) + l31 * 2;
        op[0] = o0;
        op[1] = o1;
    }
}

// ---------------------------------------------------------------------------
extern "C" void kernel_launch(void* const* d_in, const int* in_sizes, int n_in,
                              void* d_out, int out_size, void* d_ws, size_t ws_size,
                              hipStream_t stream)
{
    const float* x       = (const float*)d_in[0];
    const int*   ei      = (const int*)d_in[1];
    const float* W       = (const float*)d_in[2];
    const float* att_src = (const float*)d_in[3];
    const float* att_dst = (const float*)d_in[4];
    const float* bias    = (const float*)d_in[5];
    float* out = (float*)d_out;

    const int N = in_sizes[0] / 256;       // 50000
    const int E = in_sizes[1] / 2;         // 800000
    const int Etot = E + N;                // 850000
    const int NBUCK = (N + 63) >> BSH;     // 782
    const int NB = (Etot + EPB - 1) / EPB; // 208
    const int Ntot = NBUCK * NB;           // ~163k
    const int NCH = (Ntot + 1023) / 1024;  // 159 scan chunks
    const int GB = (N + 127) / 128;        // 391 gemm blocks

    // workspace carve (~35 MB; ws >= 56 MB)
    char* p = (char*)d_ws;
    short*    hb      = (short*)p;    p += (size_t)N * 256 * sizeof(short);
    short*    Wt      = (short*)p;    p += 256 * 256 * sizeof(short);
    float*    a_src_n = (float*)p;    p += (size_t)N * 4 * sizeof(float);
    float*    a_dst_n = (float*)p;    p += (size_t)N * 4 * sizeof(float);
    int*      hist2d  = (int*)p;      p += (size_t)Ntot * sizeof(int);
    int*      scanned = (int*)p;      p += (size_t)Ntot * sizeof(int);
    int*      bsum    = (int*)p;      p += 1024 * sizeof(int);
    int*      off     = (int*)p;      p += (size_t)(N + 1) * sizeof(int);
    unsigned* bucketed= (unsigned*)p; p += (size_t)Etot * sizeof(unsigned);
    int*      csr     = (int*)p;      p += (size_t)Etot * sizeof(int);

    prep_count<<<256 + NB, 256, NBUCK * sizeof(int), stream>>>(
        W, Wt, off, ei, hist2d, E, N, NBUCK, NB, Etot);
    scan1<<<NCH, 1024, 0, stream>>>(hist2d, scanned, bsum, Ntot);
    gemm_scatter<<<GB + NB, 512, 16384, stream>>>(
        x, Wt, att_src, att_dst, hb, a_src_n, a_dst_n, N, GB,
        ei, scanned, bsum, bucketed, E, N, NBUCK, NB, NCH);
    csr_build<<<NBUCK, 256, 0, stream>>>(bucketed, scanned, bsum, off, csr,
                                         N, NB, NBUCK, Etot, NCH);
    aggregate<<<(N + 3) / 4, 256, 0, stream>>>(hb, a_src_n, a_dst_n, off, csr,
                                               bias, out, N);
}